// Round 1
// baseline (30077.682 us; speedup 1.0000x reference)
//
#include <hip/hip_runtime.h>
#include <math.h>

#define PAD 2

// ---- ordered-uint encoding for float atomicMax ----
__device__ __forceinline__ unsigned f2o(float f){
    unsigned b = __float_as_uint(f);
    return (b & 0x80000000u) ? ~b : (b | 0x80000000u);
}
__device__ __forceinline__ float o2f(unsigned u){
    return __uint_as_float((u & 0x80000000u) ? (u & 0x7fffffffu) : ~u);
}

// ============================================================
// corr: corr[b,k,y,x] = sum_c key[b,c,y,x]*frame[b,c,y+di,x+dj]
// block = (64 pixels) x (4 channel groups); LDS reduce; fused global max
// ============================================================
__global__ void corr_kernel(const float* __restrict__ key, const float* __restrict__ frame,
                            float* __restrict__ corr, unsigned* __restrict__ gmax,
                            int C, int H, int W){
    const int HW = H * W;
    int tx = threadIdx.x, ty = threadIdx.y;
    int p = blockIdx.x * 64 + tx;
    int b = p / HW; int rem = p - b * HW; int y = rem / W; int x = rem - y * W;
    int Cq = C >> 2;
    int c0 = ty * Cq;

    float acc[25];
    #pragma unroll
    for (int k = 0; k < 25; k++) acc[k] = 0.f;

    const float* kp = key   + ((size_t)b * C + c0) * HW + rem;
    const float* fp = frame + ((size_t)b * C + c0) * HW + rem;

    // precompute offsets/validity (fixed over c)
    int off[25]; float msk[25];
    #pragma unroll
    for (int i = 0; i < 5; i++){
        int yy = y + i - PAD; bool vy = (yy >= 0) && (yy < H);
        #pragma unroll
        for (int j = 0; j < 5; j++){
            int xx = x + j - PAD; bool v = vy && (xx >= 0) && (xx < W);
            off[i*5+j] = v ? (i - PAD) * W + (j - PAD) : 0;
            msk[i*5+j] = v ? 1.f : 0.f;
        }
    }

    for (int c = 0; c < Cq; c++){
        float kv = kp[(size_t)c * HW];
        const float* f0 = fp + (size_t)c * HW;
        #pragma unroll
        for (int k = 0; k < 25; k++)
            acc[k] += kv * (f0[off[k]] * msk[k]);
    }

    __shared__ float red[25][4][64];
    #pragma unroll
    for (int k = 0; k < 25; k++) red[k][ty][tx] = acc[k];
    __syncthreads();

    if (ty == 0){
        float m = -INFINITY;
        #pragma unroll
        for (int k = 0; k < 25; k++){
            float v = red[k][0][tx] + red[k][1][tx] + red[k][2][tx] + red[k][3][tx];
            corr[((size_t)b * 25 + k) * HW + rem] = v;
            m = fmaxf(m, v);
        }
        #pragma unroll
        for (int o = 32; o > 0; o >>= 1) m = fmaxf(m, __shfl_down(m, o));
        if (tx == 0) atomicMax(gmax, f2o(m));
    }
}

// ============================================================
// warp: att = softmax_k(corr * 20/gmax); new[b,c,y,x] = sum_k att*frame[...]
// ============================================================
__global__ void warp_kernel(const float* __restrict__ frame, const float* __restrict__ corr,
                            const unsigned* __restrict__ gmax, float* __restrict__ newf,
                            int C, int H, int W){
    const int HW = H * W;
    int tx = threadIdx.x, ty = threadIdx.y;
    int p = blockIdx.x * 64 + tx;
    int b = p / HW; int rem = p - b * HW; int y = rem / W; int x = rem - y * W;

    float scale = 20.f / o2f(*gmax);
    float z[25]; float m = -INFINITY;
    #pragma unroll
    for (int k = 0; k < 25; k++){
        z[k] = corr[((size_t)b * 25 + k) * HW + rem] * scale;
        m = fmaxf(m, z[k]);
    }
    float s = 0.f;
    #pragma unroll
    for (int k = 0; k < 25; k++){ z[k] = expf(z[k] - m); s += z[k]; }
    float inv = 1.f / s;

    int off[25];
    #pragma unroll
    for (int i = 0; i < 5; i++){
        int yy = y + i - PAD; bool vy = (yy >= 0) && (yy < H);
        #pragma unroll
        for (int j = 0; j < 5; j++){
            int xx = x + j - PAD; bool v = vy && (xx >= 0) && (xx < W);
            z[i*5+j] = v ? z[i*5+j] * inv : 0.f;   // invalid taps contribute 0
            off[i*5+j] = v ? (i - PAD) * W + (j - PAD) : 0;
        }
    }

    int Cq = C >> 2; int c0 = ty * Cq;
    const float* fp = frame + ((size_t)b * C + c0) * HW + rem;
    float* op = newf + ((size_t)b * C + c0) * HW + rem;
    for (int c = 0; c < Cq; c++){
        const float* f0 = fp + (size_t)c * HW;
        float a = 0.f;
        #pragma unroll
        for (int k = 0; k < 25; k++) a += z[k] * f0[off[k]];
        op[(size_t)c * HW] = a;
    }
}

// ============================================================
// gate: g = sigmoid(conv3x3(concat[key,new], Wg_s, bg_s)), 2 out channels
// block = 64 pixels x 4 channel groups over 2C; LDS reduce
// ============================================================
__global__ void gate_kernel(const float* __restrict__ key, const float* __restrict__ newf,
                            const float* __restrict__ Wg, const float* __restrict__ bg,
                            float* __restrict__ g, int C, int H, int W){
    const int HW = H * W;
    int tx = threadIdx.x, ty = threadIdx.y;
    int p = blockIdx.x * 64 + tx;
    int b = p / HW; int rem = p - b * HW; int y = rem / W; int x = rem - y * W;

    int half = C >> 1;          // channels per group over 2C total
    int u0 = ty * half;
    const float* in = (u0 < C) ? (key  + ((size_t)b * C + u0) * HW)
                               : (newf + ((size_t)b * C + (u0 - C)) * HW);

    int off[9]; float msk[9];
    #pragma unroll
    for (int t = 0; t < 9; t++){
        int dy = t / 3 - 1, dx = t % 3 - 1;
        int yy = y + dy, xx = x + dx;
        bool v = (yy >= 0) && (yy < H) && (xx >= 0) && (xx < W);
        off[t] = v ? dy * W + dx : 0;
        msk[t] = v ? 1.f : 0.f;
    }

    float acc0 = 0.f, acc1 = 0.f;
    for (int uu = 0; uu < half; uu++){
        int u = u0 + uu;
        const float* ip = in + (size_t)uu * HW + rem;
        const float* w0 = Wg + (size_t)u * 9;
        const float* w1 = Wg + ((size_t)2 * C + u) * 9;
        #pragma unroll
        for (int t = 0; t < 9; t++){
            float v = ip[off[t]] * msk[t];
            acc0 += v * w0[t];
            acc1 += v * w1[t];
        }
    }

    __shared__ float sg[2][4][64];
    sg[0][ty][tx] = acc0; sg[1][ty][tx] = acc1;
    __syncthreads();
    if (ty == 0){
        float z0 = sg[0][0][tx] + sg[0][1][tx] + sg[0][2][tx] + sg[0][3][tx] + bg[0];
        float z1 = sg[1][0][tx] + sg[1][1][tx] + sg[1][2][tx] + sg[1][3][tx] + bg[1];
        g[((size_t)b * 2 + 0) * HW + rem] = 1.f / (1.f + expf(-z0));
        g[((size_t)b * 2 + 1) * HW + rem] = 1.f / (1.f + expf(-z1));
    }
}

// ============================================================
// conv_d: relu(conv3x3(concat[key*g0, new*g1], Wd_s, bd_s)) -> tot[:, cOff:cOff+C]
// thread computes 4 consecutive output channels (amortizes input loads)
// ============================================================
__global__ void convd_kernel(const float* __restrict__ key, const float* __restrict__ newf,
                             const float* __restrict__ g, const float* __restrict__ Wd,
                             const float* __restrict__ bd, float* __restrict__ tot,
                             int cOff, int C, int H, int W){
    const int HW = H * W;
    size_t o = (size_t)blockIdx.x * 256 + threadIdx.x;
    int x  = (int)(o % W);
    int y  = (int)((o / W) % H);
    int cg = (int)((o / HW) % (C >> 2));
    int b  = (int)(o / ((size_t)HW * (C >> 2)));
    int co0 = cg * 4;
    int rem = y * W + x;

    float g0v[9], g1v[9]; int off[9];
    const float* g0p = g + ((size_t)b * 2 + 0) * HW + rem;
    const float* g1p = g + ((size_t)b * 2 + 1) * HW + rem;
    #pragma unroll
    for (int t = 0; t < 9; t++){
        int dy = t / 3 - 1, dx = t % 3 - 1;
        int yy = y + dy, xx = x + dx;
        bool v = (yy >= 0) && (yy < H) && (xx >= 0) && (xx < W);
        int of = v ? dy * W + dx : 0;
        off[t] = of;
        g0v[t] = v ? g0p[of] : 0.f;
        g1v[t] = v ? g1p[of] : 0.f;
    }

    float acc[4];
    #pragma unroll
    for (int i = 0; i < 4; i++) acc[i] = bd[co0 + i];

    const float* kp = key  + (size_t)b * C * HW + rem;
    const float* np = newf + (size_t)b * C * HW + rem;
    const size_t wstr = (size_t)2 * C * 9;
    const float* w0 = Wd + (size_t)co0 * wstr;

    for (int u = 0; u < C; u++){
        const float* ip = kp + (size_t)u * HW;
        const float* wp = w0 + (size_t)u * 9;
        #pragma unroll
        for (int t = 0; t < 9; t++){
            float fv = ip[off[t]] * g0v[t];
            #pragma unroll
            for (int i = 0; i < 4; i++) acc[i] += fv * wp[i * wstr + t];
        }
    }
    for (int u = 0; u < C; u++){
        const float* ip = np + (size_t)u * HW;
        const float* wp = w0 + (size_t)(C + u) * 9;
        #pragma unroll
        for (int t = 0; t < 9; t++){
            float fv = ip[off[t]] * g1v[t];
            #pragma unroll
            for (int i = 0; i < 4; i++) acc[i] += fv * wp[i * wstr + t];
        }
    }

    float* op = tot + ((size_t)b * 3 * C + cOff + co0) * HW + rem;
    #pragma unroll
    for (int i = 0; i < 4; i++) op[(size_t)i * HW] = fmaxf(acc[i], 0.f);
}

// ============================================================
// conv_c: relu(conv3x3(tot, Wc, bc)) -> out
// ============================================================
__global__ void convc_kernel(const float* __restrict__ in, const float* __restrict__ Wc,
                             const float* __restrict__ bc, float* __restrict__ out,
                             int Cin, int Cout, int H, int W){
    const int HW = H * W;
    size_t o = (size_t)blockIdx.x * 256 + threadIdx.x;
    int x  = (int)(o % W);
    int y  = (int)((o / W) % H);
    int cg = (int)((o / HW) % (Cout >> 2));
    int b  = (int)(o / ((size_t)HW * (Cout >> 2)));
    int co0 = cg * 4;
    int rem = y * W + x;

    int off[9]; float msk[9];
    #pragma unroll
    for (int t = 0; t < 9; t++){
        int dy = t / 3 - 1, dx = t % 3 - 1;
        int yy = y + dy, xx = x + dx;
        bool v = (yy >= 0) && (yy < H) && (xx >= 0) && (xx < W);
        off[t] = v ? dy * W + dx : 0;
        msk[t] = v ? 1.f : 0.f;
    }

    float acc[4];
    #pragma unroll
    for (int i = 0; i < 4; i++) acc[i] = bc[co0 + i];

    const float* ip0 = in + (size_t)b * Cin * HW + rem;
    const size_t wstr = (size_t)Cin * 9;
    const float* w0 = Wc + (size_t)co0 * wstr;

    for (int u = 0; u < Cin; u++){
        const float* ip = ip0 + (size_t)u * HW;
        const float* wp = w0 + (size_t)u * 9;
        #pragma unroll
        for (int t = 0; t < 9; t++){
            float fv = ip[off[t]] * msk[t];
            #pragma unroll
            for (int i = 0; i < 4; i++) acc[i] += fv * wp[i * wstr + t];
        }
    }

    float* op = out + ((size_t)b * Cout + co0) * HW + rem;
    #pragma unroll
    for (int i = 0; i < 4; i++) op[(size_t)i * HW] = fmaxf(acc[i], 0.f);
}

// ============================================================
extern "C" void kernel_launch(void* const* d_in, const int* in_sizes, int n_in,
                              void* d_out, int out_size, void* d_ws, size_t ws_size,
                              hipStream_t stream){
    (void)in_sizes; (void)n_in; (void)out_size; (void)ws_size;

    const float* X[4][2];
    for (int s = 0; s < 4; s++)
        for (int l = 0; l < 2; l++)
            X[s][l] = (const float*)d_in[s * 2 + l];
    const float* Wg[2] = { (const float*)d_in[8],  (const float*)d_in[14] };
    const float* bg[2] = { (const float*)d_in[9],  (const float*)d_in[15] };
    const float* Wd[2] = { (const float*)d_in[10], (const float*)d_in[16] };
    const float* bd[2] = { (const float*)d_in[11], (const float*)d_in[17] };
    const float* Wc[2] = { (const float*)d_in[12], (const float*)d_in[18] };
    const float* bc[2] = { (const float*)d_in[13], (const float*)d_in[19] };
    float* out = (float*)d_out;

    // workspace layout (bytes):
    //   [0,4096)            gmax slots (6 used)
    //   [4096, +1638400)    corr   [4,25,64,64] max
    //   [.., +16777216)     new    [4,256,64,64] max
    //   [.., +131072)       g      [4,2,64,64] max
    //   [.., +50331648)     tot    [4,768,64,64] max      total ~66 MiB
    char* ws = (char*)d_ws;
    unsigned* gmax = (unsigned*)ws;
    float* corrbuf = (float*)(ws + 4096);
    float* newbuf  = (float*)(ws + 4096 + 1638400);
    float* gbuf    = (float*)(ws + 4096 + 1638400 + 16777216);
    float* totbuf  = (float*)(ws + 4096 + 1638400 + 16777216 + 131072);

    hipMemsetAsync(gmax, 0, 64, stream);   // 0 < encoding of any finite float

    const int Cs[2] = {256, 512};
    const int Hs[2] = {64, 32};
    const size_t outOff[2] = {0, (size_t)4 * 256 * 64 * 64};

    for (int l = 0; l < 2; l++){
        const int C = Cs[l], H = Hs[l], W = Hs[l], HW = H * W;
        const float* key = X[3][l];
        const int runs = 4 * HW / 64;
        const dim3 blk(64, 4);
        for (int s = 0; s < 3; s++){
            const float* fr = X[s][l];
            unsigned* slot = gmax + (l * 3 + s);
            corr_kernel<<<runs, blk, 0, stream>>>(key, fr, corrbuf, slot, C, H, W);
            warp_kernel<<<runs, blk, 0, stream>>>(fr, corrbuf, slot, newbuf, C, H, W);
            gate_kernel<<<runs, blk, 0, stream>>>(key, newbuf,
                                                  Wg[l] + (size_t)s * 2 * (2 * C) * 9,
                                                  bg[l] + (size_t)s * 2, gbuf, C, H, W);
            int blocks_d = 4 * (C / 4) * HW / 256;
            convd_kernel<<<blocks_d, 256, 0, stream>>>(key, newbuf, gbuf,
                                                       Wd[l] + (size_t)s * C * (2 * C) * 9,
                                                       bd[l] + (size_t)s * C,
                                                       totbuf, s * C, C, H, W);
        }
        int blocks_c = 4 * (C / 4) * HW / 256;
        convc_kernel<<<blocks_c, 256, 0, stream>>>(totbuf, Wc[l], bc[l],
                                                   out + outOff[l], 3 * C, C, H, W);
    }
}

// Round 2
// 4330.872 us; speedup vs baseline: 6.9449x; 6.9449x over previous
//
#include <hip/hip_runtime.h>
#include <hip/hip_bf16.h>
#include <math.h>

#define PAD 2

typedef __attribute__((ext_vector_type(8))) short s8v;    // 8 bf16 = 4 VGPRs
typedef __attribute__((ext_vector_type(4))) float f4v;    // 4 fp32 acc

__device__ __forceinline__ f4v mfma16(s8v a, s8v b, f4v c){
    return __builtin_amdgcn_mfma_f32_16x16x32_bf16(a, b, c, 0, 0, 0);
}

__device__ __forceinline__ void gl_lds16(const void* g, void* l){
    __builtin_amdgcn_global_load_lds(
        (const __attribute__((address_space(1))) void*)g,
        (__attribute__((address_space(3))) void*)l, 16, 0, 0);
}

__device__ __forceinline__ unsigned short f2bf(float f){
    unsigned u = __float_as_uint(f);
    unsigned r = u + 0x7FFFu + ((u >> 16) & 1u);
    return (unsigned short)(r >> 16);
}

// ---- ordered-uint encoding for float atomicMax ----
__device__ __forceinline__ unsigned f2o(float f){
    unsigned b = __float_as_uint(f);
    return (b & 0x80000000u) ? ~b : (b | 0x80000000u);
}
__device__ __forceinline__ float o2f(unsigned u){
    return __uint_as_float((u & 0x80000000u) ? (u & 0x7fffffffu) : ~u);
}

// ============================================================
// corr (unchanged, fp32): corr[b,k,y,x] + fused global max
// ============================================================
__global__ void corr_kernel(const float* __restrict__ key, const float* __restrict__ frame,
                            float* __restrict__ corr, unsigned* __restrict__ gmax,
                            int C, int H, int W){
    const int HW = H * W;
    int tx = threadIdx.x, ty = threadIdx.y;
    int p = blockIdx.x * 64 + tx;
    int b = p / HW; int rem = p - b * HW; int y = rem / W; int x = rem - y * W;
    int Cq = C >> 2;
    int c0 = ty * Cq;

    float acc[25];
    #pragma unroll
    for (int k = 0; k < 25; k++) acc[k] = 0.f;

    const float* kp = key   + ((size_t)b * C + c0) * HW + rem;
    const float* fp = frame + ((size_t)b * C + c0) * HW + rem;

    int off[25]; float msk[25];
    #pragma unroll
    for (int i = 0; i < 5; i++){
        int yy = y + i - PAD; bool vy = (yy >= 0) && (yy < H);
        #pragma unroll
        for (int j = 0; j < 5; j++){
            int xx = x + j - PAD; bool v = vy && (xx >= 0) && (xx < W);
            off[i*5+j] = v ? (i - PAD) * W + (j - PAD) : 0;
            msk[i*5+j] = v ? 1.f : 0.f;
        }
    }

    for (int c = 0; c < Cq; c++){
        float kv = kp[(size_t)c * HW];
        const float* f0 = fp + (size_t)c * HW;
        #pragma unroll
        for (int k = 0; k < 25; k++)
            acc[k] += kv * (f0[off[k]] * msk[k]);
    }

    __shared__ float red[25][4][64];
    #pragma unroll
    for (int k = 0; k < 25; k++) red[k][ty][tx] = acc[k];
    __syncthreads();

    if (ty == 0){
        float m = -INFINITY;
        #pragma unroll
        for (int k = 0; k < 25; k++){
            float v = red[k][0][tx] + red[k][1][tx] + red[k][2][tx] + red[k][3][tx];
            corr[((size_t)b * 25 + k) * HW + rem] = v;
            m = fmaxf(m, v);
        }
        #pragma unroll
        for (int o = 32; o > 0; o >>= 1) m = fmaxf(m, __shfl_down(m, o));
        if (tx == 0) atomicMax(gmax, f2o(m));
    }
}

// ============================================================
// warp (unchanged, fp32)
// ============================================================
__global__ void warp_kernel(const float* __restrict__ frame, const float* __restrict__ corr,
                            const unsigned* __restrict__ gmax, float* __restrict__ newf,
                            int C, int H, int W){
    const int HW = H * W;
    int tx = threadIdx.x, ty = threadIdx.y;
    int p = blockIdx.x * 64 + tx;
    int b = p / HW; int rem = p - b * HW; int y = rem / W; int x = rem - y * W;

    float scale = 20.f / o2f(*gmax);
    float z[25]; float m = -INFINITY;
    #pragma unroll
    for (int k = 0; k < 25; k++){
        z[k] = corr[((size_t)b * 25 + k) * HW + rem] * scale;
        m = fmaxf(m, z[k]);
    }
    float s = 0.f;
    #pragma unroll
    for (int k = 0; k < 25; k++){ z[k] = expf(z[k] - m); s += z[k]; }
    float inv = 1.f / s;

    int off[25];
    #pragma unroll
    for (int i = 0; i < 5; i++){
        int yy = y + i - PAD; bool vy = (yy >= 0) && (yy < H);
        #pragma unroll
        for (int j = 0; j < 5; j++){
            int xx = x + j - PAD; bool v = vy && (xx >= 0) && (xx < W);
            z[i*5+j] = v ? z[i*5+j] * inv : 0.f;
            off[i*5+j] = v ? (i - PAD) * W + (j - PAD) : 0;
        }
    }

    int Cq = C >> 2; int c0 = ty * Cq;
    const float* fp = frame + ((size_t)b * C + c0) * HW + rem;
    float* op = newf + ((size_t)b * C + c0) * HW + rem;
    for (int c = 0; c < Cq; c++){
        const float* f0 = fp + (size_t)c * HW;
        float a = 0.f;
        #pragma unroll
        for (int k = 0; k < 25; k++) a += z[k] * f0[off[k]];
        op[(size_t)c * HW] = a;
    }
}

// ============================================================
// gate (unchanged, fp32)
// ============================================================
__global__ void gate_kernel(const float* __restrict__ key, const float* __restrict__ newf,
                            const float* __restrict__ Wg, const float* __restrict__ bg,
                            float* __restrict__ g, int C, int H, int W){
    const int HW = H * W;
    int tx = threadIdx.x, ty = threadIdx.y;
    int p = blockIdx.x * 64 + tx;
    int b = p / HW; int rem = p - b * HW; int y = rem / W; int x = rem - y * W;

    int half = C >> 1;
    int u0 = ty * half;
    const float* in = (u0 < C) ? (key  + ((size_t)b * C + u0) * HW)
                               : (newf + ((size_t)b * C + (u0 - C)) * HW);

    int off[9]; float msk[9];
    #pragma unroll
    for (int t = 0; t < 9; t++){
        int dy = t / 3 - 1, dx = t % 3 - 1;
        int yy = y + dy, xx = x + dx;
        bool v = (yy >= 0) && (yy < H) && (xx >= 0) && (xx < W);
        off[t] = v ? dy * W + dx : 0;
        msk[t] = v ? 1.f : 0.f;
    }

    float acc0 = 0.f, acc1 = 0.f;
    for (int uu = 0; uu < half; uu++){
        int u = u0 + uu;
        const float* ip = in + (size_t)uu * HW + rem;
        const float* w0 = Wg + (size_t)u * 9;
        const float* w1 = Wg + ((size_t)2 * C + u) * 9;
        #pragma unroll
        for (int t = 0; t < 9; t++){
            float v = ip[off[t]] * msk[t];
            acc0 += v * w0[t];
            acc1 += v * w1[t];
        }
    }

    __shared__ float sg[2][4][64];
    sg[0][ty][tx] = acc0; sg[1][ty][tx] = acc1;
    __syncthreads();
    if (ty == 0){
        float z0 = sg[0][0][tx] + sg[0][1][tx] + sg[0][2][tx] + sg[0][3][tx] + bg[0];
        float z1 = sg[1][0][tx] + sg[1][1][tx] + sg[1][2][tx] + sg[1][3][tx] + bg[1];
        g[((size_t)b * 2 + 0) * HW + rem] = 1.f / (1.f + expf(-z0));
        g[((size_t)b * 2 + 1) * HW + rem] = 1.f / (1.f + expf(-z1));
    }
}

// ============================================================
// prep_gin: NCHW fp32 (key,new) * gate -> NHWC bf16 gin[b*HW][2C]
// 64p x 64u tile via LDS transpose
// ============================================================
__global__ void prep_gin(const float* __restrict__ key, const float* __restrict__ newf,
                         const float* __restrict__ g, unsigned short* __restrict__ gin,
                         int C, int HW){
    __shared__ unsigned short tile[64][65];
    int tid = threadIdx.x;
    int pt0 = blockIdx.x * 64;
    int u0  = blockIdx.y * 64;
    int b   = pt0 / HW;
    int rem0 = pt0 - b * HW;
    const float* gb = g + (size_t)(b * 2) * HW;

    #pragma unroll
    for (int it = 0; it < 16; it++){
        int idx = it * 256 + tid;
        int ur = idx >> 6, pc = idx & 63;
        int u = u0 + ur; int rem = rem0 + pc;
        const float* src; int sel;
        if (u < C){ src = key  + ((size_t)b * C + u) * HW;       sel = 0; }
        else      { src = newf + ((size_t)b * C + (u - C)) * HW; sel = 1; }
        float v = src[rem] * gb[(size_t)sel * HW + rem];
        tile[ur][pc] = f2bf(v);
    }
    __syncthreads();
    unsigned short* go = gin + (size_t)pt0 * (2 * C) + u0;
    #pragma unroll
    for (int it = 0; it < 16; it++){
        int idx = it * 256 + tid;
        int pr = idx >> 6, uc = idx & 63;
        go[(size_t)pr * (2 * C) + uc] = tile[uc][pr];
    }
}

// ============================================================
// prep_w: W[co][ci][t] fp32 -> Wt[co][t*Cin+ci] bf16
// grid (Cout*9, Cin/256)
// ============================================================
__global__ void prep_w(const float* __restrict__ W, unsigned short* __restrict__ Wt,
                       int Cin){
    int ci = blockIdx.y * 256 + threadIdx.x;
    int bx = blockIdx.x;
    int co = bx / 9, t = bx - co * 9;
    Wt[(size_t)bx * Cin + ci] = f2bf(W[((size_t)co * Cin + ci) * 9 + t]);
}

// ============================================================
// conv_mfma: implicit-GEMM 3x3 conv, bf16 MFMA 16x16x32
//   A (M=pixels) = gin NHWC bf16 gathered with per-tap offset
//   B (N=cout)   = Wt [co][t*Cin+ci]
// BM=128, BN in {64,128}; 256 threads = 4 waves, 2x2 wave grid,
// m97-style 2-barrier K-loop with width-16 global_load_lds.
// EPI=0: write tot NHWC bf16 slice (+bias,relu); EPI=1: NCHW fp32 out.
// ============================================================
template<int BN, int EPI>
__global__ __launch_bounds__(256, 1)
void conv_mfma(const unsigned short* __restrict__ gin,
               const unsigned short* __restrict__ Wt,
               const float* __restrict__ bias,
               unsigned short* __restrict__ obf, int ostride,
               float* __restrict__ of32,
               const void* __restrict__ zp,
               int Cin, int Cout, int H, int W, int logHW, int logW)
{
    constexpr int BM = 128;
    constexpr int BNh = BN / 2;
    constexpr int NJ = BN / 32;
    __shared__ __align__(16) unsigned short sA[BM * 32];
    __shared__ __align__(16) unsigned short sB[BN * 32];

    const int tid = threadIdx.x;
    const int lane = tid & 63;
    const int wv = tid >> 6;
    const int wm = wv >> 1, wn = wv & 1;
    const int ln = lane & 15, q = lane >> 4;

    const int bx = blockIdx.x, by = blockIdx.y;
    const int p0 = bx * BM;
    const int b  = p0 >> logHW;
    const int rem0 = p0 - (b << logHW);

    // A staging: slot = wv*64 + lane (+256); row = slot>>2, chunk = slot&3
    const int rowA0 = tid >> 2, chA = tid & 3;
    const int rowA1 = rowA0 + 64;
    const int remA0 = rem0 + rowA0, remA1 = rem0 + rowA1;
    const int yA0 = remA0 >> logW, xA0 = remA0 & (W - 1);
    const int yA1 = remA1 >> logW, xA1 = remA1 & (W - 1);
    const size_t pbase = ((size_t)b << logHW);

    // B staging: slot = tid (+256 if BN==128); row = slot>>2
    const int rowB0 = tid >> 2;
    const int nt0 = by * BN;
    const size_t Ktot = (size_t)9 * Cin;

    f4v acc[4][NJ];
    #pragma unroll
    for (int i = 0; i < 4; i++)
        #pragma unroll
        for (int j = 0; j < NJ; j++){ f4v z = {0.f, 0.f, 0.f, 0.f}; acc[i][j] = z; }

    char* sAb = (char*)sA;
    char* sBb = (char*)sB;
    const int cblocks = Cin >> 5;
    int kb = 0;
    for (int t = 0; t < 9; t++){
        const int dy = t / 3 - 1, dx = t % 3 - 1;
        const int dof = dy * W + dx;
        const bool v0 = ((unsigned)(yA0 + dy) < (unsigned)H) && ((unsigned)(xA0 + dx) < (unsigned)W);
        const bool v1 = ((unsigned)(yA1 + dy) < (unsigned)H) && ((unsigned)(xA1 + dx) < (unsigned)W);
        const unsigned short* a0 = gin + (pbase + remA0 + dof) * Cin + chA * 8;
        const unsigned short* a1 = gin + (pbase + remA1 + dof) * Cin + chA * 8;
        for (int cb = 0; cb < cblocks; cb++, kb++){
            const int ci0 = cb * 32;
            // --- stage A (128 rows x 32 k, bf16, dense [row][32]) ---
            gl_lds16(v0 ? (const void*)(a0 + ci0) : zp, sAb + wv * 1024);
            gl_lds16(v1 ? (const void*)(a1 + ci0) : zp, sAb + 4096 + wv * 1024);
            // --- stage B ---
            const unsigned short* wb = Wt + (size_t)(nt0 + rowB0) * Ktot + kb * 32 + chA * 8;
            gl_lds16((const void*)wb, sBb + wv * 1024);
            if (BN == 128){
                const unsigned short* wb1 = Wt + (size_t)(nt0 + rowB0 + 64) * Ktot + kb * 32 + chA * 8;
                gl_lds16((const void*)wb1, sBb + 4096 + wv * 1024);
            }
            __syncthreads();
            s8v af[4];
            #pragma unroll
            for (int i = 0; i < 4; i++)
                af[i] = *(const s8v*)(sA + (wm * 64 + i * 16 + ln) * 32 + q * 8);
            #pragma unroll
            for (int j = 0; j < NJ; j++){
                s8v bfr = *(const s8v*)(sB + (wn * BNh + j * 16 + ln) * 32 + q * 8);
                #pragma unroll
                for (int i = 0; i < 4; i++)
                    acc[i][j] = mfma16(af[i], bfr, acc[i][j]);
            }
            __syncthreads();
        }
    }

    // epilogue: D rows m = quad*4+reg (pixels), cols n = lane&15 (cout)
    #pragma unroll
    for (int i = 0; i < 4; i++){
        const int m0 = wm * 64 + i * 16 + q * 4;
        const int p = p0 + m0;
        #pragma unroll
        for (int j = 0; j < NJ; j++){
            const int n = nt0 + wn * BNh + j * 16 + ln;
            const float bv = bias[n];
            if (EPI == 0){
                #pragma unroll
                for (int r = 0; r < 4; r++){
                    float v = fmaxf(acc[i][j][r] + bv, 0.f);
                    obf[(size_t)(p + r) * ostride + n] = f2bf(v);
                }
            } else {
                f4v o;
                #pragma unroll
                for (int r = 0; r < 4; r++) o[r] = fmaxf(acc[i][j][r] + bv, 0.f);
                const int rem = rem0 + m0;
                *(f4v*)(of32 + (((size_t)b * Cout + n) << logHW) + rem) = o;
            }
        }
    }
}

// ============================================================
extern "C" void kernel_launch(void* const* d_in, const int* in_sizes, int n_in,
                              void* d_out, int out_size, void* d_ws, size_t ws_size,
                              hipStream_t stream){
    (void)in_sizes; (void)n_in; (void)out_size; (void)ws_size;

    const float* X[4][2];
    for (int s = 0; s < 4; s++)
        for (int l = 0; l < 2; l++)
            X[s][l] = (const float*)d_in[s * 2 + l];
    const float* Wg[2] = { (const float*)d_in[8],  (const float*)d_in[14] };
    const float* bg[2] = { (const float*)d_in[9],  (const float*)d_in[15] };
    const float* Wd[2] = { (const float*)d_in[10], (const float*)d_in[16] };
    const float* bd[2] = { (const float*)d_in[11], (const float*)d_in[17] };
    const float* Wc[2] = { (const float*)d_in[12], (const float*)d_in[18] };
    const float* bc[2] = { (const float*)d_in[13], (const float*)d_in[19] };
    float* out = (float*)d_out;

    // workspace layout (bytes):
    //   [0,1024)    gmax slots (6 used)
    //   [1024,4096) zero page (16B zeros for OOB global_load_lds)
    //   corr   1,638,400   (4*25*4096*4)
    //   newf  16,777,216   (4*256*4096*4)  [ALIASED by Wt bf16, max 14.2MB —
    //                       prep_w runs only after last read of newf each s]
    //   g        131,072
    //   gin   16,777,216   (16384 px * 512 ch * 2B max)
    //   tot   25,165,824   (16384 px * 768 ch * 2B max)     total ~57.7MB
    char* ws = (char*)d_ws;
    unsigned* gmax = (unsigned*)ws;
    const void* zp = (const void*)(ws + 1024);
    float* corrbuf = (float*)(ws + 4096);
    float* newbuf  = (float*)(ws + 4096 + 1638400);
    unsigned short* wtbuf = (unsigned short*)newbuf;   // alias, disjoint lifetime
    float* gbuf    = (float*)(ws + 4096 + 1638400 + 16777216);
    unsigned short* ginbuf = (unsigned short*)(ws + 4096 + 1638400 + 16777216 + 131072);
    unsigned short* totbuf = (unsigned short*)(ws + 4096 + 1638400 + 16777216 + 131072 + 16777216);

    hipMemsetAsync(ws, 0, 4096, stream);

    const int Cs[2] = {256, 512};
    const int Hs[2] = {64, 32};
    const int logWs[2] = {6, 5};
    const int logHWs[2] = {12, 10};
    const size_t outOff[2] = {0, (size_t)4 * 256 * 4096};

    for (int l = 0; l < 2; l++){
        const int C = Cs[l], H = Hs[l], W = Hs[l], HW = H * W;
        const int logW = logWs[l], logHW = logHWs[l];
        const float* key = X[3][l];
        const int runs = 4 * HW / 64;          // pixel blocks for corr/warp/gate
        const dim3 blk(64, 4);
        const int Mt = 4 * HW / 128;           // GEMM M-tiles

        for (int s = 0; s < 3; s++){
            const float* fr = X[s][l];
            unsigned* slot = gmax + (l * 3 + s);
            corr_kernel<<<runs, blk, 0, stream>>>(key, fr, corrbuf, slot, C, H, W);
            warp_kernel<<<runs, blk, 0, stream>>>(fr, corrbuf, slot, newbuf, C, H, W);
            gate_kernel<<<runs, blk, 0, stream>>>(key, newbuf,
                                                  Wg[l] + (size_t)s * 2 * (2 * C) * 9,
                                                  bg[l] + (size_t)s * 2, gbuf, C, H, W);
            prep_gin<<<dim3(4 * HW / 64, 2 * C / 64), 256, 0, stream>>>(
                key, newbuf, gbuf, ginbuf, C, HW);
            prep_w<<<dim3(C * 9, 2 * C / 256), 256, 0, stream>>>(
                Wd[l] + (size_t)s * C * 2 * C * 9, wtbuf, 2 * C);
            if (l == 0)
                conv_mfma<128, 0><<<dim3(Mt, C / 128), 256, 0, stream>>>(
                    ginbuf, wtbuf, bd[l] + s * C, totbuf + s * C, 3 * C,
                    nullptr, zp, 2 * C, C, H, W, logHW, logW);
            else
                conv_mfma<64, 0><<<dim3(Mt, C / 64), 256, 0, stream>>>(
                    ginbuf, wtbuf, bd[l] + s * C, totbuf + s * C, 3 * C,
                    nullptr, zp, 2 * C, C, H, W, logHW, logW);
        }
        prep_w<<<dim3(C * 9, 3 * C / 256), 256, 0, stream>>>(Wc[l], wtbuf, 3 * C);
        if (l == 0)
            conv_mfma<128, 1><<<dim3(Mt, C / 128), 256, 0, stream>>>(
                totbuf, wtbuf, bc[l], nullptr, 0,
                out + outOff[l], zp, 3 * C, C, H, W, logHW, logW);
        else
            conv_mfma<64, 1><<<dim3(Mt, C / 64), 256, 0, stream>>>(
                totbuf, wtbuf, bc[l], nullptr, 0,
                out + outOff[l], zp, 3 * C, C, H, W, logHW, logW);
    }
}

// Round 3
// 2930.342 us; speedup vs baseline: 10.2642x; 1.4779x over previous
//
#include <hip/hip_runtime.h>
#include <hip/hip_bf16.h>
#include <math.h>

#define PAD 2

typedef __attribute__((ext_vector_type(8))) short s8v;    // 8 bf16 = 4 VGPRs
typedef __attribute__((ext_vector_type(4))) float f4v;    // 4 fp32 acc

__device__ __forceinline__ f4v mfma16(s8v a, s8v b, f4v c){
    return __builtin_amdgcn_mfma_f32_16x16x32_bf16(a, b, c, 0, 0, 0);
}

__device__ __forceinline__ void gl_lds16(const void* g, void* l){
    __builtin_amdgcn_global_load_lds(
        (const __attribute__((address_space(1))) void*)g,
        (__attribute__((address_space(3))) void*)l, 16, 0, 0);
}

__device__ __forceinline__ unsigned short f2bf(float f){
    unsigned u = __float_as_uint(f);
    unsigned r = u + 0x7FFFu + ((u >> 16) & 1u);
    return (unsigned short)(r >> 16);
}

// ---- ordered-uint encoding for float atomicMax ----
__device__ __forceinline__ unsigned f2o(float f){
    unsigned b = __float_as_uint(f);
    return (b & 0x80000000u) ? ~b : (b | 0x80000000u);
}
__device__ __forceinline__ float o2f(unsigned u){
    return __uint_as_float((u & 0x80000000u) ? (u & 0x7fffffffu) : ~u);
}

// ============================================================
// corr v2: thread = (pixel, k). grid = (4HW/256, 25).
// scalar acc -> no spills; 1600/400 blocks -> real occupancy.
// fused wave-max -> atomicMax(gmax).
// ============================================================
__global__ void corr_kernel(const float* __restrict__ key, const float* __restrict__ frame,
                            float* __restrict__ corr, unsigned* __restrict__ gmax,
                            int C, int H, int W, int logHW, int logW){
    const int HW = H * W;
    const int k = blockIdx.y;
    const int di = k / 5 - PAD, dj = (k % 5) - PAD;
    const int p = blockIdx.x * 256 + threadIdx.x;
    const int b = p >> logHW;
    const int rem = p & (HW - 1);
    const int y = rem >> logW, x = rem & (W - 1);
    const bool v = ((unsigned)(y + di) < (unsigned)H) && ((unsigned)(x + dj) < (unsigned)W);
    const int off = v ? di * W + dj : 0;

    const float* kp = key   + (((size_t)b * C) << logHW) + rem;
    const float* fp = frame + (((size_t)b * C) << logHW) + rem + off;

    float acc = 0.f;
    #pragma unroll 4
    for (int c = 0; c < C; c++)
        acc += kp[c * HW] * fp[c * HW];
    acc = v ? acc : 0.f;   // reference pads frame with zeros

    corr[(((size_t)b * 25 + k) << logHW) + rem] = acc;

    float m = acc;
    #pragma unroll
    for (int o = 32; o > 0; o >>= 1) m = fmaxf(m, __shfl_down(m, o));
    if ((threadIdx.x & 63) == 0) atomicMax(gmax, f2o(m));
}

// ============================================================
// att: softmax over the 25 offsets, in-place on corr buffer.
// thread = pixel. grid = 4HW/256.
// ============================================================
__global__ void att_kernel(float* __restrict__ corr, const unsigned* __restrict__ gmax,
                           int logHW){
    const int p = blockIdx.x * 256 + threadIdx.x;
    const int b = p >> logHW;
    const int rem = p & ((1 << logHW) - 1);
    float* cp = corr + (((size_t)b * 25) << logHW) + rem;
    const float scale = 20.f / o2f(*gmax);

    float z[25]; float m = -INFINITY;
    #pragma unroll
    for (int k = 0; k < 25; k++){
        z[k] = cp[k << logHW] * scale;
        m = fmaxf(m, z[k]);
    }
    float s = 0.f;
    #pragma unroll
    for (int k = 0; k < 25; k++){ z[k] = expf(z[k] - m); s += z[k]; }
    const float inv = 1.f / s;
    #pragma unroll
    for (int k = 0; k < 25; k++) cp[k << logHW] = z[k] * inv;
}

// ============================================================
// warp_gather: new[b,c,p] = sum_k att[b,k,p] * frame[b,c,p+off_k] (masked)
// thread = (c, pixel). grid = (4HW/256, C). fully unrolled 25 taps.
// ============================================================
__global__ void warp_gather(const float* __restrict__ frame, const float* __restrict__ att,
                            float* __restrict__ newf,
                            int C, int H, int W, int logHW, int logW){
    const int c = blockIdx.y;
    const int p = blockIdx.x * 256 + threadIdx.x;
    const int b = p >> logHW;
    const int rem = p & ((1 << logHW) - 1);
    const int y = rem >> logW, x = rem & (W - 1);

    const float* ap = att   + (((size_t)b * 25) << logHW) + rem;
    const float* fp = frame + (((size_t)b * C + c) << logHW) + rem;

    float acc = 0.f;
    #pragma unroll
    for (int i = 0; i < 5; i++){
        #pragma unroll
        for (int j = 0; j < 5; j++){
            const int k = i * 5 + j;
            const bool v = ((unsigned)(y + i - PAD) < (unsigned)H) &&
                           ((unsigned)(x + j - PAD) < (unsigned)W);
            const int off = v ? (i - PAD) * W + (j - PAD) : 0;
            acc += ap[k << logHW] * (fp[off] * (v ? 1.f : 0.f));
        }
    }
    newf[(((size_t)b * C + c) << logHW) + rem] = acc;
}

// ============================================================
// gate (unchanged, fp32)
// ============================================================
__global__ void gate_kernel(const float* __restrict__ key, const float* __restrict__ newf,
                            const float* __restrict__ Wg, const float* __restrict__ bg,
                            float* __restrict__ g, int C, int H, int W){
    const int HW = H * W;
    int tx = threadIdx.x, ty = threadIdx.y;
    int p = blockIdx.x * 64 + tx;
    int b = p / HW; int rem = p - b * HW; int y = rem / W; int x = rem - y * W;

    int half = C >> 1;
    int u0 = ty * half;
    const float* in = (u0 < C) ? (key  + ((size_t)b * C + u0) * HW)
                               : (newf + ((size_t)b * C + (u0 - C)) * HW);

    int off[9]; float msk[9];
    #pragma unroll
    for (int t = 0; t < 9; t++){
        int dy = t / 3 - 1, dx = t % 3 - 1;
        int yy = y + dy, xx = x + dx;
        bool v = (yy >= 0) && (yy < H) && (xx >= 0) && (xx < W);
        off[t] = v ? dy * W + dx : 0;
        msk[t] = v ? 1.f : 0.f;
    }

    float acc0 = 0.f, acc1 = 0.f;
    for (int uu = 0; uu < half; uu++){
        int u = u0 + uu;
        const float* ip = in + (size_t)uu * HW + rem;
        const float* w0 = Wg + (size_t)u * 9;
        const float* w1 = Wg + ((size_t)2 * C + u) * 9;
        #pragma unroll
        for (int t = 0; t < 9; t++){
            float v = ip[off[t]] * msk[t];
            acc0 += v * w0[t];
            acc1 += v * w1[t];
        }
    }

    __shared__ float sg[2][4][64];
    sg[0][ty][tx] = acc0; sg[1][ty][tx] = acc1;
    __syncthreads();
    if (ty == 0){
        float z0 = sg[0][0][tx] + sg[0][1][tx] + sg[0][2][tx] + sg[0][3][tx] + bg[0];
        float z1 = sg[1][0][tx] + sg[1][1][tx] + sg[1][2][tx] + sg[1][3][tx] + bg[1];
        g[((size_t)b * 2 + 0) * HW + rem] = 1.f / (1.f + expf(-z0));
        g[((size_t)b * 2 + 1) * HW + rem] = 1.f / (1.f + expf(-z1));
    }
}

// ============================================================
// prep_gin: NCHW fp32 (key,new) * gate -> NHWC bf16 gin[b*HW][2C]
// ============================================================
__global__ void prep_gin(const float* __restrict__ key, const float* __restrict__ newf,
                         const float* __restrict__ g, unsigned short* __restrict__ gin,
                         int C, int HW){
    __shared__ unsigned short tile[64][65];
    int tid = threadIdx.x;
    int pt0 = blockIdx.x * 64;
    int u0  = blockIdx.y * 64;
    int b   = pt0 / HW;
    int rem0 = pt0 - b * HW;
    const float* gb = g + (size_t)(b * 2) * HW;

    #pragma unroll
    for (int it = 0; it < 16; it++){
        int idx = it * 256 + tid;
        int ur = idx >> 6, pc = idx & 63;
        int u = u0 + ur; int rem = rem0 + pc;
        const float* src; int sel;
        if (u < C){ src = key  + ((size_t)b * C + u) * HW;       sel = 0; }
        else      { src = newf + ((size_t)b * C + (u - C)) * HW; sel = 1; }
        float v = src[rem] * gb[(size_t)sel * HW + rem];
        tile[ur][pc] = f2bf(v);
    }
    __syncthreads();
    unsigned short* go = gin + (size_t)pt0 * (2 * C) + u0;
    #pragma unroll
    for (int it = 0; it < 16; it++){
        int idx = it * 256 + tid;
        int pr = idx >> 6, uc = idx & 63;
        go[(size_t)pr * (2 * C) + uc] = tile[uc][pr];
    }
}

// ============================================================
// prep_w: W[co][ci][t] fp32 -> Wt[co][t*Cin+ci] bf16
// ============================================================
__global__ void prep_w(const float* __restrict__ W, unsigned short* __restrict__ Wt,
                       int Cin){
    int ci = blockIdx.y * 256 + threadIdx.x;
    int bx = blockIdx.x;
    int co = bx / 9, t = bx - co * 9;
    Wt[(size_t)bx * Cin + ci] = f2bf(W[((size_t)co * Cin + ci) * 9 + t]);
}

// ============================================================
// conv_mfma: implicit-GEMM 3x3 conv, bf16 MFMA 16x16x32 (unchanged)
// ============================================================
template<int BN, int EPI>
__global__ __launch_bounds__(256, 1)
void conv_mfma(const unsigned short* __restrict__ gin,
               const unsigned short* __restrict__ Wt,
               const float* __restrict__ bias,
               unsigned short* __restrict__ obf, int ostride,
               float* __restrict__ of32,
               const void* __restrict__ zp,
               int Cin, int Cout, int H, int W, int logHW, int logW)
{
    constexpr int BM = 128;
    constexpr int BNh = BN / 2;
    constexpr int NJ = BN / 32;
    __shared__ __align__(16) unsigned short sA[BM * 32];
    __shared__ __align__(16) unsigned short sB[BN * 32];

    const int tid = threadIdx.x;
    const int lane = tid & 63;
    const int wv = tid >> 6;
    const int wm = wv >> 1, wn = wv & 1;
    const int ln = lane & 15, q = lane >> 4;

    const int bx = blockIdx.x, by = blockIdx.y;
    const int p0 = bx * BM;
    const int b  = p0 >> logHW;
    const int rem0 = p0 - (b << logHW);

    const int rowA0 = tid >> 2, chA = tid & 3;
    const int rowA1 = rowA0 + 64;
    const int remA0 = rem0 + rowA0, remA1 = rem0 + rowA1;
    const int yA0 = remA0 >> logW, xA0 = remA0 & (W - 1);
    const int yA1 = remA1 >> logW, xA1 = remA1 & (W - 1);
    const size_t pbase = ((size_t)b << logHW);

    const int rowB0 = tid >> 2;
    const int nt0 = by * BN;
    const size_t Ktot = (size_t)9 * Cin;

    f4v acc[4][NJ];
    #pragma unroll
    for (int i = 0; i < 4; i++)
        #pragma unroll
        for (int j = 0; j < NJ; j++){ f4v z = {0.f, 0.f, 0.f, 0.f}; acc[i][j] = z; }

    char* sAb = (char*)sA;
    char* sBb = (char*)sB;
    const int cblocks = Cin >> 5;
    int kb = 0;
    for (int t = 0; t < 9; t++){
        const int dy = t / 3 - 1, dx = t % 3 - 1;
        const int dof = dy * W + dx;
        const bool v0 = ((unsigned)(yA0 + dy) < (unsigned)H) && ((unsigned)(xA0 + dx) < (unsigned)W);
        const bool v1 = ((unsigned)(yA1 + dy) < (unsigned)H) && ((unsigned)(xA1 + dx) < (unsigned)W);
        const unsigned short* a0 = gin + (pbase + remA0 + dof) * Cin + chA * 8;
        const unsigned short* a1 = gin + (pbase + remA1 + dof) * Cin + chA * 8;
        for (int cb = 0; cb < cblocks; cb++, kb++){
            const int ci0 = cb * 32;
            gl_lds16(v0 ? (const void*)(a0 + ci0) : zp, sAb + wv * 1024);
            gl_lds16(v1 ? (const void*)(a1 + ci0) : zp, sAb + 4096 + wv * 1024);
            const unsigned short* wb = Wt + (size_t)(nt0 + rowB0) * Ktot + kb * 32 + chA * 8;
            gl_lds16((const void*)wb, sBb + wv * 1024);
            if (BN == 128){
                const unsigned short* wb1 = Wt + (size_t)(nt0 + rowB0 + 64) * Ktot + kb * 32 + chA * 8;
                gl_lds16((const void*)wb1, sBb + 4096 + wv * 1024);
            }
            __syncthreads();
            s8v af[4];
            #pragma unroll
            for (int i = 0; i < 4; i++)
                af[i] = *(const s8v*)(sA + (wm * 64 + i * 16 + ln) * 32 + q * 8);
            #pragma unroll
            for (int j = 0; j < NJ; j++){
                s8v bfr = *(const s8v*)(sB + (wn * BNh + j * 16 + ln) * 32 + q * 8);
                #pragma unroll
                for (int i = 0; i < 4; i++)
                    acc[i][j] = mfma16(af[i], bfr, acc[i][j]);
            }
            __syncthreads();
        }
    }

    #pragma unroll
    for (int i = 0; i < 4; i++){
        const int m0 = wm * 64 + i * 16 + q * 4;
        const int p = p0 + m0;
        #pragma unroll
        for (int j = 0; j < NJ; j++){
            const int n = nt0 + wn * BNh + j * 16 + ln;
            const float bv = bias[n];
            if (EPI == 0){
                #pragma unroll
                for (int r = 0; r < 4; r++){
                    float v = fmaxf(acc[i][j][r] + bv, 0.f);
                    obf[(size_t)(p + r) * ostride + n] = f2bf(v);
                }
            } else {
                f4v o;
                #pragma unroll
                for (int r = 0; r < 4; r++) o[r] = fmaxf(acc[i][j][r] + bv, 0.f);
                const int rem = rem0 + m0;
                *(f4v*)(of32 + (((size_t)b * Cout + n) << logHW) + rem) = o;
            }
        }
    }
}

// ============================================================
extern "C" void kernel_launch(void* const* d_in, const int* in_sizes, int n_in,
                              void* d_out, int out_size, void* d_ws, size_t ws_size,
                              hipStream_t stream){
    (void)in_sizes; (void)n_in; (void)out_size; (void)ws_size;

    const float* X[4][2];
    for (int s = 0; s < 4; s++)
        for (int l = 0; l < 2; l++)
            X[s][l] = (const float*)d_in[s * 2 + l];
    const float* Wg[2] = { (const float*)d_in[8],  (const float*)d_in[14] };
    const float* bg[2] = { (const float*)d_in[9],  (const float*)d_in[15] };
    const float* Wd[2] = { (const float*)d_in[10], (const float*)d_in[16] };
    const float* bd[2] = { (const float*)d_in[11], (const float*)d_in[17] };
    const float* Wc[2] = { (const float*)d_in[12], (const float*)d_in[18] };
    const float* bc[2] = { (const float*)d_in[13], (const float*)d_in[19] };
    float* out = (float*)d_out;

    char* ws = (char*)d_ws;
    unsigned* gmax = (unsigned*)ws;
    const void* zp = (const void*)(ws + 1024);
    float* corrbuf = (float*)(ws + 4096);
    float* newbuf  = (float*)(ws + 4096 + 1638400);
    unsigned short* wtbuf = (unsigned short*)newbuf;   // alias, disjoint lifetime
    float* gbuf    = (float*)(ws + 4096 + 1638400 + 16777216);
    unsigned short* ginbuf = (unsigned short*)(ws + 4096 + 1638400 + 16777216 + 131072);
    unsigned short* totbuf = (unsigned short*)(ws + 4096 + 1638400 + 16777216 + 131072 + 16777216);

    hipMemsetAsync(ws, 0, 4096, stream);

    const int Cs[2] = {256, 512};
    const int Hs[2] = {64, 32};
    const int logWs[2] = {6, 5};
    const int logHWs[2] = {12, 10};
    const size_t outOff[2] = {0, (size_t)4 * 256 * 4096};

    for (int l = 0; l < 2; l++){
        const int C = Cs[l], H = Hs[l], W = Hs[l], HW = H * W;
        const int logW = logWs[l], logHW = logHWs[l];
        const float* key = X[3][l];
        const int pblk = 4 * HW / 256;         // pixel blocks (256 threads)
        const dim3 gblk(64, 4);
        const int Mt = 4 * HW / 128;           // GEMM M-tiles

        for (int s = 0; s < 3; s++){
            const float* fr = X[s][l];
            unsigned* slot = gmax + (l * 3 + s);
            corr_kernel<<<dim3(pblk, 25), 256, 0, stream>>>(
                key, fr, corrbuf, slot, C, H, W, logHW, logW);
            att_kernel<<<pblk, 256, 0, stream>>>(corrbuf, slot, logHW);
            warp_gather<<<dim3(pblk, C), 256, 0, stream>>>(
                fr, corrbuf, newbuf, C, H, W, logHW, logW);
            gate_kernel<<<4 * HW / 64, gblk, 0, stream>>>(
                key, newbuf, Wg[l] + (size_t)s * 2 * (2 * C) * 9,
                bg[l] + (size_t)s * 2, gbuf, C, H, W);
            prep_gin<<<dim3(4 * HW / 64, 2 * C / 64), 256, 0, stream>>>(
                key, newbuf, gbuf, ginbuf, C, HW);
            prep_w<<<dim3(C * 9, 2 * C / 256), 256, 0, stream>>>(
                Wd[l] + (size_t)s * C * 2 * C * 9, wtbuf, 2 * C);
            if (l == 0)
                conv_mfma<128, 0><<<dim3(Mt, C / 128), 256, 0, stream>>>(
                    ginbuf, wtbuf, bd[l] + s * C, totbuf + s * C, 3 * C,
                    nullptr, zp, 2 * C, C, H, W, logHW, logW);
            else
                conv_mfma<64, 0><<<dim3(Mt, C / 64), 256, 0, stream>>>(
                    ginbuf, wtbuf, bd[l] + s * C, totbuf + s * C, 3 * C,
                    nullptr, zp, 2 * C, C, H, W, logHW, logW);
        }
        prep_w<<<dim3(C * 9, 3 * C / 256), 256, 0, stream>>>(Wc[l], wtbuf, 3 * C);
        if (l == 0)
            conv_mfma<128, 1><<<dim3(Mt, C / 128), 256, 0, stream>>>(
                totbuf, wtbuf, bc[l], nullptr, 0,
                out + outOff[l], zp, 3 * C, C, H, W, logHW, logW);
        else
            conv_mfma<64, 1><<<dim3(Mt, C / 64), 256, 0, stream>>>(
                totbuf, wtbuf, bc[l], nullptr, 0,
                out + outOff[l], zp, 3 * C, C, H, W, logHW, logW);
    }
}

// Round 4
// 2871.621 us; speedup vs baseline: 10.4741x; 1.0204x over previous
//
#include <hip/hip_runtime.h>
#include <hip/hip_bf16.h>
#include <math.h>

#define PAD 2

typedef __attribute__((ext_vector_type(8))) short s8v;    // 8 bf16 = 4 VGPRs
typedef __attribute__((ext_vector_type(4))) float f4v;    // 4 fp32 acc

__device__ __forceinline__ f4v mfma16(s8v a, s8v b, f4v c){
    return __builtin_amdgcn_mfma_f32_16x16x32_bf16(a, b, c, 0, 0, 0);
}

__device__ __forceinline__ void gl_lds16(const void* g, void* l){
    __builtin_amdgcn_global_load_lds(
        (const __attribute__((address_space(1))) void*)g,
        (__attribute__((address_space(3))) void*)l, 16, 0, 0);
}

__device__ __forceinline__ unsigned short f2bf(float f){
    unsigned u = __float_as_uint(f);
    unsigned r = u + 0x7FFFu + ((u >> 16) & 1u);
    return (unsigned short)(r >> 16);
}

// ---- ordered-uint encoding for float atomicMax ----
__device__ __forceinline__ unsigned f2o(float f){
    unsigned b = __float_as_uint(f);
    return (b & 0x80000000u) ? ~b : (b | 0x80000000u);
}
__device__ __forceinline__ float o2f(unsigned u){
    return __uint_as_float((u & 0x80000000u) ? (u & 0x7fffffffu) : ~u);
}

// ============================================================
// corr: thread = (pixel, k). grid = (4HW/256, 25).
// ============================================================
__global__ void corr_kernel(const float* __restrict__ key, const float* __restrict__ frame,
                            float* __restrict__ corr, unsigned* __restrict__ gmax,
                            int C, int H, int W, int logHW, int logW){
    const int HW = H * W;
    const int k = blockIdx.y;
    const int di = k / 5 - PAD, dj = (k % 5) - PAD;
    const int p = blockIdx.x * 256 + threadIdx.x;
    const int b = p >> logHW;
    const int rem = p & (HW - 1);
    const int y = rem >> logW, x = rem & (W - 1);
    const bool v = ((unsigned)(y + di) < (unsigned)H) && ((unsigned)(x + dj) < (unsigned)W);
    const int off = v ? di * W + dj : 0;

    const float* kp = key   + (((size_t)b * C) << logHW) + rem;
    const float* fp = frame + (((size_t)b * C) << logHW) + rem + off;

    float acc = 0.f;
    #pragma unroll 4
    for (int c = 0; c < C; c++)
        acc += kp[c * HW] * fp[c * HW];
    acc = v ? acc : 0.f;

    corr[(((size_t)b * 25 + k) << logHW) + rem] = acc;

    float m = acc;
    #pragma unroll
    for (int o = 32; o > 0; o >>= 1) m = fmaxf(m, __shfl_down(m, o));
    if ((threadIdx.x & 63) == 0) atomicMax(gmax, f2o(m));
}

// ============================================================
// att: softmax over the 25 offsets, in-place on corr buffer.
// ============================================================
__global__ void att_kernel(float* __restrict__ corr, const unsigned* __restrict__ gmax,
                           int logHW){
    const int p = blockIdx.x * 256 + threadIdx.x;
    const int b = p >> logHW;
    const int rem = p & ((1 << logHW) - 1);
    float* cp = corr + (((size_t)b * 25) << logHW) + rem;
    const float scale = 20.f / o2f(*gmax);

    float z[25]; float m = -INFINITY;
    #pragma unroll
    for (int k = 0; k < 25; k++){
        z[k] = cp[k << logHW] * scale;
        m = fmaxf(m, z[k]);
    }
    float s = 0.f;
    #pragma unroll
    for (int k = 0; k < 25; k++){ z[k] = expf(z[k] - m); s += z[k]; }
    const float inv = 1.f / s;
    #pragma unroll
    for (int k = 0; k < 25; k++) cp[k << logHW] = z[k] * inv;
}

// ============================================================
// warp_gather: thread = (c, pixel). grid = (4HW/256, C).
// ============================================================
__global__ void warp_gather(const float* __restrict__ frame, const float* __restrict__ att,
                            float* __restrict__ newf,
                            int C, int H, int W, int logHW, int logW){
    const int c = blockIdx.y;
    const int p = blockIdx.x * 256 + threadIdx.x;
    const int b = p >> logHW;
    const int rem = p & ((1 << logHW) - 1);
    const int y = rem >> logW, x = rem & (W - 1);

    const float* ap = att   + (((size_t)b * 25) << logHW) + rem;
    const float* fp = frame + (((size_t)b * C + c) << logHW) + rem;

    float acc = 0.f;
    #pragma unroll
    for (int i = 0; i < 5; i++){
        #pragma unroll
        for (int j = 0; j < 5; j++){
            const int k = i * 5 + j;
            const bool v = ((unsigned)(y + i - PAD) < (unsigned)H) &&
                           ((unsigned)(x + j - PAD) < (unsigned)W);
            const int off = v ? (i - PAD) * W + (j - PAD) : 0;
            acc += ap[k << logHW] * (fp[off] * (v ? 1.f : 0.f));
        }
    }
    newf[(((size_t)b * C + c) << logHW) + rem] = acc;
}

// ============================================================
// gate (unchanged, fp32)
// ============================================================
__global__ void gate_kernel(const float* __restrict__ key, const float* __restrict__ newf,
                            const float* __restrict__ Wg, const float* __restrict__ bg,
                            float* __restrict__ g, int C, int H, int W){
    const int HW = H * W;
    int tx = threadIdx.x, ty = threadIdx.y;
    int p = blockIdx.x * 64 + tx;
    int b = p / HW; int rem = p - b * HW; int y = rem / W; int x = rem - y * W;

    int half = C >> 1;
    int u0 = ty * half;
    const float* in = (u0 < C) ? (key  + ((size_t)b * C + u0) * HW)
                               : (newf + ((size_t)b * C + (u0 - C)) * HW);

    int off[9]; float msk[9];
    #pragma unroll
    for (int t = 0; t < 9; t++){
        int dy = t / 3 - 1, dx = t % 3 - 1;
        int yy = y + dy, xx = x + dx;
        bool v = (yy >= 0) && (yy < H) && (xx >= 0) && (xx < W);
        off[t] = v ? dy * W + dx : 0;
        msk[t] = v ? 1.f : 0.f;
    }

    float acc0 = 0.f, acc1 = 0.f;
    for (int uu = 0; uu < half; uu++){
        int u = u0 + uu;
        const float* ip = in + (size_t)uu * HW + rem;
        const float* w0 = Wg + (size_t)u * 9;
        const float* w1 = Wg + ((size_t)2 * C + u) * 9;
        #pragma unroll
        for (int t = 0; t < 9; t++){
            float v = ip[off[t]] * msk[t];
            acc0 += v * w0[t];
            acc1 += v * w1[t];
        }
    }

    __shared__ float sg[2][4][64];
    sg[0][ty][tx] = acc0; sg[1][ty][tx] = acc1;
    __syncthreads();
    if (ty == 0){
        float z0 = sg[0][0][tx] + sg[0][1][tx] + sg[0][2][tx] + sg[0][3][tx] + bg[0];
        float z1 = sg[1][0][tx] + sg[1][1][tx] + sg[1][2][tx] + sg[1][3][tx] + bg[1];
        g[((size_t)b * 2 + 0) * HW + rem] = 1.f / (1.f + expf(-z0));
        g[((size_t)b * 2 + 1) * HW + rem] = 1.f / (1.f + expf(-z1));
    }
}

// ============================================================
// prep_gin: NCHW fp32 (key,new) * gate -> NHWC bf16 gin[b*HW][2C]
// ============================================================
__global__ void prep_gin(const float* __restrict__ key, const float* __restrict__ newf,
                         const float* __restrict__ g, unsigned short* __restrict__ gin,
                         int C, int HW){
    __shared__ unsigned short tile[64][65];
    int tid = threadIdx.x;
    int pt0 = blockIdx.x * 64;
    int u0  = blockIdx.y * 64;
    int b   = pt0 / HW;
    int rem0 = pt0 - b * HW;
    const float* gb = g + (size_t)(b * 2) * HW;

    #pragma unroll
    for (int it = 0; it < 16; it++){
        int idx = it * 256 + tid;
        int ur = idx >> 6, pc = idx & 63;
        int u = u0 + ur; int rem = rem0 + pc;
        const float* src; int sel;
        if (u < C){ src = key  + ((size_t)b * C + u) * HW;       sel = 0; }
        else      { src = newf + ((size_t)b * C + (u - C)) * HW; sel = 1; }
        float v = src[rem] * gb[(size_t)sel * HW + rem];
        tile[ur][pc] = f2bf(v);
    }
    __syncthreads();
    unsigned short* go = gin + (size_t)pt0 * (2 * C) + u0;
    #pragma unroll
    for (int it = 0; it < 16; it++){
        int idx = it * 256 + tid;
        int pr = idx >> 6, uc = idx & 63;
        go[(size_t)pr * (2 * C) + uc] = tile[uc][pr];
    }
}

// ============================================================
// prep_w: W[co][ci][t] fp32 -> Wt[co][t*Cin+ci] bf16
// ============================================================
__global__ void prep_w(const float* __restrict__ W, unsigned short* __restrict__ Wt,
                       int Cin){
    int ci = blockIdx.y * 256 + threadIdx.x;
    int bx = blockIdx.x;
    int co = bx / 9, t = bx - co * 9;
    Wt[(size_t)bx * Cin + ci] = f2bf(W[((size_t)co * Cin + ci) * 9 + t]);
}

// ============================================================
// conv_mfma v2: implicit-GEMM 3x3 conv, bf16 MFMA 16x16x32.
// Changes vs v1:
//  - XOR-swizzled LDS chunk layout: phys chunk = q ^ ((row>>1)&3)
//    -> ds_read_b128 8-way bank conflict becomes 2-way (free).
//  - double-buffered LDS, ONE barrier per K-block; stage k+1 issued
//    right after the barrier so its latency overlaps compute of k.
// ============================================================
template<int BN, int EPI>
__global__ __launch_bounds__(256, 1)
void conv_mfma(const unsigned short* __restrict__ gin,
               const unsigned short* __restrict__ Wt,
               const float* __restrict__ bias,
               unsigned short* __restrict__ obf, int ostride,
               float* __restrict__ of32,
               const void* __restrict__ zp,
               int Cin, int Cout, int H, int W, int logHW, int logW)
{
    constexpr int BM = 128;
    constexpr int BNh = BN / 2;
    constexpr int NJ = BN / 32;
    __shared__ __align__(16) unsigned short sA[2][BM * 32];
    __shared__ __align__(16) unsigned short sB[2][BN * 32];

    const int tid = threadIdx.x;
    const int lane = tid & 63;
    const int wv = tid >> 6;
    const int wm = wv >> 1, wn = wv & 1;
    const int ln = lane & 15, q = lane >> 4;

    const int p0 = blockIdx.x * BM;
    const int b  = p0 >> logHW;
    const int rem0 = p0 - (b << logHW);

    // staging: slot = tid; row = tid>>2; swizzled global chunk
    const int rowA0 = tid >> 2;
    const int gc8 = ((tid & 3) ^ ((tid >> 3) & 3)) * 8;    // element offset
    const int remA0 = rem0 + rowA0, remA1 = remA0 + 64;
    const int yA0 = remA0 >> logW, xA0 = remA0 & (W - 1);
    const int yA1 = remA1 >> logW, xA1 = remA1 & (W - 1);
    const size_t pbase = ((size_t)b << logHW);

    const int nt0 = blockIdx.y * BN;
    const size_t Ktot = (size_t)9 * Cin;
    const unsigned short* wB0 = Wt + (size_t)(nt0 + rowA0) * Ktot + gc8;
    const unsigned short* wB1 = wB0 + 64 * Ktot;

    f4v acc[4][NJ];
    #pragma unroll
    for (int i = 0; i < 4; i++)
        #pragma unroll
        for (int j = 0; j < NJ; j++){ f4v z = {0.f, 0.f, 0.f, 0.f}; acc[i][j] = z; }

    const int cblocks = Cin >> 5;
    const int total = 9 * cblocks;

    // tap state for the tile currently being staged (starts at t=0: dy=-1,dx=-1)
    int t_cur = 0;
    bool v0 = (yA0 > 0) && (xA0 > 0);
    bool v1 = (yA1 > 0) && (xA1 > 0);
    const unsigned short* a0 = gin + (pbase + remA0 + (-W - 1)) * Cin + gc8;
    const unsigned short* a1 = gin + (pbase + remA1 + (-W - 1)) * Cin + gc8;

    // prologue: stage K-block 0 into buf 0
    {
        char* dA = (char*)sA[0];
        gl_lds16(v0 ? (const void*)a0 : zp, dA + wv * 1024);
        gl_lds16(v1 ? (const void*)a1 : zp, dA + 4096 + wv * 1024);
        char* dB = (char*)sB[0];
        gl_lds16((const void*)wB0, dB + wv * 1024);
        if (BN == 128) gl_lds16((const void*)wB1, dB + 4096 + wv * 1024);
    }

    const int rchunk = (q ^ ((ln >> 1) & 3)) * 8;   // swizzled read offset
    int cb = 0;
    for (int kb = 0; kb < total; kb++){
        __syncthreads();   // drains vmcnt(0): buf[kb&1] loads (issued last iter) done

        if (kb + 1 < total){
            int cbn = cb + 1;
            if (cbn == cblocks){
                cbn = 0;
                t_cur++;
                const int dy = t_cur / 3 - 1, dx = t_cur % 3 - 1;
                const int dof = dy * W + dx;
                v0 = ((unsigned)(yA0 + dy) < (unsigned)H) && ((unsigned)(xA0 + dx) < (unsigned)W);
                v1 = ((unsigned)(yA1 + dy) < (unsigned)H) && ((unsigned)(xA1 + dx) < (unsigned)W);
                a0 = gin + (pbase + remA0 + dof) * Cin + gc8;
                a1 = gin + (pbase + remA1 + dof) * Cin + gc8;
            }
            const int nb = (kb + 1) & 1;
            char* dA = (char*)sA[nb];
            gl_lds16(v0 ? (const void*)(a0 + cbn * 32) : zp, dA + wv * 1024);
            gl_lds16(v1 ? (const void*)(a1 + cbn * 32) : zp, dA + 4096 + wv * 1024);
            char* dB = (char*)sB[nb];
            gl_lds16((const void*)(wB0 + (kb + 1) * 32), dB + wv * 1024);
            if (BN == 128) gl_lds16((const void*)(wB1 + (kb + 1) * 32), dB + 4096 + wv * 1024);
            cb = cbn;
        }

        const unsigned short* A = sA[kb & 1];
        const unsigned short* B = sB[kb & 1];
        s8v af[4];
        #pragma unroll
        for (int i = 0; i < 4; i++)
            af[i] = *(const s8v*)(A + (wm * 64 + i * 16 + ln) * 32 + rchunk);
        #pragma unroll
        for (int j = 0; j < NJ; j++){
            s8v bfr = *(const s8v*)(B + (wn * BNh + j * 16 + ln) * 32 + rchunk);
            #pragma unroll
            for (int i = 0; i < 4; i++)
                acc[i][j] = mfma16(af[i], bfr, acc[i][j]);
        }
    }

    // epilogue: D rows m = q*4+r (pixels), cols n = ln (cout)
    #pragma unroll
    for (int i = 0; i < 4; i++){
        const int m0 = wm * 64 + i * 16 + q * 4;
        const int p = p0 + m0;
        #pragma unroll
        for (int j = 0; j < NJ; j++){
            const int n = nt0 + wn * BNh + j * 16 + ln;
            const float bv = bias[n];
            if (EPI == 0){
                #pragma unroll
                for (int r = 0; r < 4; r++){
                    float v = fmaxf(acc[i][j][r] + bv, 0.f);
                    obf[(size_t)(p + r) * ostride + n] = f2bf(v);
                }
            } else {
                f4v o;
                #pragma unroll
                for (int r = 0; r < 4; r++) o[r] = fmaxf(acc[i][j][r] + bv, 0.f);
                const int rem = rem0 + m0;
                *(f4v*)(of32 + (((size_t)b * Cout + n) << logHW) + rem) = o;
            }
        }
    }
}

// ============================================================
extern "C" void kernel_launch(void* const* d_in, const int* in_sizes, int n_in,
                              void* d_out, int out_size, void* d_ws, size_t ws_size,
                              hipStream_t stream){
    (void)in_sizes; (void)n_in; (void)out_size; (void)ws_size;

    const float* X[4][2];
    for (int s = 0; s < 4; s++)
        for (int l = 0; l < 2; l++)
            X[s][l] = (const float*)d_in[s * 2 + l];
    const float* Wg[2] = { (const float*)d_in[8],  (const float*)d_in[14] };
    const float* bg[2] = { (const float*)d_in[9],  (const float*)d_in[15] };
    const float* Wd[2] = { (const float*)d_in[10], (const float*)d_in[16] };
    const float* bd[2] = { (const float*)d_in[11], (const float*)d_in[17] };
    const float* Wc[2] = { (const float*)d_in[12], (const float*)d_in[18] };
    const float* bc[2] = { (const float*)d_in[13], (const float*)d_in[19] };
    float* out = (float*)d_out;

    char* ws = (char*)d_ws;
    unsigned* gmax = (unsigned*)ws;
    const void* zp = (const void*)(ws + 1024);
    float* corrbuf = (float*)(ws + 4096);
    float* newbuf  = (float*)(ws + 4096 + 1638400);
    unsigned short* wtbuf = (unsigned short*)newbuf;   // alias, disjoint lifetime
    float* gbuf    = (float*)(ws + 4096 + 1638400 + 16777216);
    unsigned short* ginbuf = (unsigned short*)(ws + 4096 + 1638400 + 16777216 + 131072);
    unsigned short* totbuf = (unsigned short*)(ws + 4096 + 1638400 + 16777216 + 131072 + 16777216);

    hipMemsetAsync(ws, 0, 4096, stream);

    const int Cs[2] = {256, 512};
    const int Hs[2] = {64, 32};
    const int logWs[2] = {6, 5};
    const int logHWs[2] = {12, 10};
    const size_t outOff[2] = {0, (size_t)4 * 256 * 4096};

    for (int l = 0; l < 2; l++){
        const int C = Cs[l], H = Hs[l], W = Hs[l], HW = H * W;
        const int logW = logWs[l], logHW = logHWs[l];
        const float* key = X[3][l];
        const int pblk = 4 * HW / 256;
        const dim3 gblk(64, 4);
        const int Mt = 4 * HW / 128;

        for (int s = 0; s < 3; s++){
            const float* fr = X[s][l];
            unsigned* slot = gmax + (l * 3 + s);
            corr_kernel<<<dim3(pblk, 25), 256, 0, stream>>>(
                key, fr, corrbuf, slot, C, H, W, logHW, logW);
            att_kernel<<<pblk, 256, 0, stream>>>(corrbuf, slot, logHW);
            warp_gather<<<dim3(pblk, C), 256, 0, stream>>>(
                fr, corrbuf, newbuf, C, H, W, logHW, logW);
            gate_kernel<<<4 * HW / 64, gblk, 0, stream>>>(
                key, newbuf, Wg[l] + (size_t)s * 2 * (2 * C) * 9,
                bg[l] + (size_t)s * 2, gbuf, C, H, W);
            prep_gin<<<dim3(4 * HW / 64, 2 * C / 64), 256, 0, stream>>>(
                key, newbuf, gbuf, ginbuf, C, HW);
            prep_w<<<dim3(C * 9, 2 * C / 256), 256, 0, stream>>>(
                Wd[l] + (size_t)s * C * 2 * C * 9, wtbuf, 2 * C);
            if (l == 0)
                conv_mfma<128, 0><<<dim3(Mt, C / 128), 256, 0, stream>>>(
                    ginbuf, wtbuf, bd[l] + s * C, totbuf + s * C, 3 * C,
                    nullptr, zp, 2 * C, C, H, W, logHW, logW);
            else
                conv_mfma<64, 0><<<dim3(Mt, C / 64), 256, 0, stream>>>(
                    ginbuf, wtbuf, bd[l] + s * C, totbuf + s * C, 3 * C,
                    nullptr, zp, 2 * C, C, H, W, logHW, logW);
        }
        prep_w<<<dim3(C * 9, 3 * C / 256), 256, 0, stream>>>(Wc[l], wtbuf, 3 * C);
        if (l == 0)
            conv_mfma<128, 1><<<dim3(Mt, C / 128), 256, 0, stream>>>(
                totbuf, wtbuf, bc[l], nullptr, 0,
                out + outOff[l], zp, 3 * C, C, H, W, logHW, logW);
        else
            conv_mfma<64, 1><<<dim3(Mt, C / 64), 256, 0, stream>>>(
                totbuf, wtbuf, bc[l], nullptr, 0,
                out + outOff[l], zp, 3 * C, C, H, W, logHW, logW);
    }
}

// Round 5
// 2807.075 us; speedup vs baseline: 10.7150x; 1.0230x over previous
//
#include <hip/hip_runtime.h>
#include <hip/hip_bf16.h>
#include <math.h>

#define PAD 2

typedef __attribute__((ext_vector_type(8))) short s8v;    // 8 bf16 = 4 VGPRs
typedef __attribute__((ext_vector_type(4))) float f4v;    // 4 fp32 acc

__device__ __forceinline__ f4v mfma16(s8v a, s8v b, f4v c){
    return __builtin_amdgcn_mfma_f32_16x16x32_bf16(a, b, c, 0, 0, 0);
}

__device__ __forceinline__ void gl_lds16(const void* g, void* l){
    __builtin_amdgcn_global_load_lds(
        (const __attribute__((address_space(1))) void*)g,
        (__attribute__((address_space(3))) void*)l, 16, 0, 0);
}

__device__ __forceinline__ unsigned short f2bf(float f){
    unsigned u = __float_as_uint(f);
    unsigned r = u + 0x7FFFu + ((u >> 16) & 1u);
    return (unsigned short)(r >> 16);
}

// ---- ordered-uint encoding for float atomicMax ----
__device__ __forceinline__ unsigned f2o(float f){
    unsigned b = __float_as_uint(f);
    return (b & 0x80000000u) ? ~b : (b | 0x80000000u);
}
__device__ __forceinline__ float o2f(unsigned u){
    return __uint_as_float((u & 0x80000000u) ? (u & 0x7fffffffu) : ~u);
}

// ============================================================
// corr: thread = (pixel, k). grid = (25, 4HW/256) — k fastest so the
// 25 blocks of one pixel tile are dispatch-adjacent (L2 locality).
// ============================================================
__global__ void corr_kernel(const float* __restrict__ key, const float* __restrict__ frame,
                            float* __restrict__ corr, unsigned* __restrict__ gmax,
                            int C, int H, int W, int logHW, int logW){
    const int HW = H * W;
    const int k = blockIdx.x;
    const int di = k / 5 - PAD, dj = (k % 5) - PAD;
    const int p = blockIdx.y * 256 + threadIdx.x;
    const int b = p >> logHW;
    const int rem = p & (HW - 1);
    const int y = rem >> logW, x = rem & (W - 1);
    const bool v = ((unsigned)(y + di) < (unsigned)H) && ((unsigned)(x + dj) < (unsigned)W);
    const int off = v ? di * W + dj : 0;

    const float* kp = key   + (((size_t)b * C) << logHW) + rem;
    const float* fp = frame + (((size_t)b * C) << logHW) + rem + off;

    float acc = 0.f;
    #pragma unroll 4
    for (int c = 0; c < C; c++)
        acc += kp[c * HW] * fp[c * HW];
    acc = v ? acc : 0.f;

    corr[(((size_t)b * 25 + k) << logHW) + rem] = acc;

    float m = acc;
    #pragma unroll
    for (int o = 32; o > 0; o >>= 1) m = fmaxf(m, __shfl_down(m, o));
    if ((threadIdx.x & 63) == 0) atomicMax(gmax, f2o(m));
}

// ============================================================
// att: softmax over the 25 offsets, in-place on corr buffer.
// ============================================================
__global__ void att_kernel(float* __restrict__ corr, const unsigned* __restrict__ gmax,
                           int logHW){
    const int p = blockIdx.x * 256 + threadIdx.x;
    const int b = p >> logHW;
    const int rem = p & ((1 << logHW) - 1);
    float* cp = corr + (((size_t)b * 25) << logHW) + rem;
    const float scale = 20.f / o2f(*gmax);

    float z[25]; float m = -INFINITY;
    #pragma unroll
    for (int k = 0; k < 25; k++){
        z[k] = cp[k << logHW] * scale;
        m = fmaxf(m, z[k]);
    }
    float s = 0.f;
    #pragma unroll
    for (int k = 0; k < 25; k++){ z[k] = expf(z[k] - m); s += z[k]; }
    const float inv = 1.f / s;
    #pragma unroll
    for (int k = 0; k < 25; k++) cp[k << logHW] = z[k] * inv;
}

// ============================================================
// warp_gather: thread = (c, pixel). grid = (4HW/256, C).
// ============================================================
__global__ void warp_gather(const float* __restrict__ frame, const float* __restrict__ att,
                            float* __restrict__ newf,
                            int C, int H, int W, int logHW, int logW){
    const int c = blockIdx.y;
    const int p = blockIdx.x * 256 + threadIdx.x;
    const int b = p >> logHW;
    const int rem = p & ((1 << logHW) - 1);
    const int y = rem >> logW, x = rem & (W - 1);

    const float* ap = att   + (((size_t)b * 25) << logHW) + rem;
    const float* fp = frame + (((size_t)b * C + c) << logHW) + rem;

    float acc = 0.f;
    #pragma unroll
    for (int i = 0; i < 5; i++){
        #pragma unroll
        for (int j = 0; j < 5; j++){
            const int k = i * 5 + j;
            const bool v = ((unsigned)(y + i - PAD) < (unsigned)H) &&
                           ((unsigned)(x + j - PAD) < (unsigned)W);
            const int off = v ? (i - PAD) * W + (j - PAD) : 0;
            acc += ap[k << logHW] * (fp[off] * (v ? 1.f : 0.f));
        }
    }
    newf[(((size_t)b * C + c) << logHW) + rem] = acc;
}

// ============================================================
// gate (unchanged, fp32)
// ============================================================
__global__ void gate_kernel(const float* __restrict__ key, const float* __restrict__ newf,
                            const float* __restrict__ Wg, const float* __restrict__ bg,
                            float* __restrict__ g, int C, int H, int W){
    const int HW = H * W;
    int tx = threadIdx.x, ty = threadIdx.y;
    int p = blockIdx.x * 64 + tx;
    int b = p / HW; int rem = p - b * HW; int y = rem / W; int x = rem - y * W;

    int half = C >> 1;
    int u0 = ty * half;
    const float* in = (u0 < C) ? (key  + ((size_t)b * C + u0) * HW)
                               : (newf + ((size_t)b * C + (u0 - C)) * HW);

    int off[9]; float msk[9];
    #pragma unroll
    for (int t = 0; t < 9; t++){
        int dy = t / 3 - 1, dx = t % 3 - 1;
        int yy = y + dy, xx = x + dx;
        bool v = (yy >= 0) && (yy < H) && (xx >= 0) && (xx < W);
        off[t] = v ? dy * W + dx : 0;
        msk[t] = v ? 1.f : 0.f;
    }

    float acc0 = 0.f, acc1 = 0.f;
    for (int uu = 0; uu < half; uu++){
        int u = u0 + uu;
        const float* ip = in + (size_t)uu * HW + rem;
        const float* w0 = Wg + (size_t)u * 9;
        const float* w1 = Wg + ((size_t)2 * C + u) * 9;
        #pragma unroll
        for (int t = 0; t < 9; t++){
            float v = ip[off[t]] * msk[t];
            acc0 += v * w0[t];
            acc1 += v * w1[t];
        }
    }

    __shared__ float sg[2][4][64];
    sg[0][ty][tx] = acc0; sg[1][ty][tx] = acc1;
    __syncthreads();
    if (ty == 0){
        float z0 = sg[0][0][tx] + sg[0][1][tx] + sg[0][2][tx] + sg[0][3][tx] + bg[0];
        float z1 = sg[1][0][tx] + sg[1][1][tx] + sg[1][2][tx] + sg[1][3][tx] + bg[1];
        g[((size_t)b * 2 + 0) * HW + rem] = 1.f / (1.f + expf(-z0));
        g[((size_t)b * 2 + 1) * HW + rem] = 1.f / (1.f + expf(-z1));
    }
}

// ============================================================
// prep_gin: NCHW fp32 (key,new) * gate -> NHWC bf16 gin[b*HW][2C]
// ============================================================
__global__ void prep_gin(const float* __restrict__ key, const float* __restrict__ newf,
                         const float* __restrict__ g, unsigned short* __restrict__ gin,
                         int C, int HW){
    __shared__ unsigned short tile[64][65];
    int tid = threadIdx.x;
    int pt0 = blockIdx.x * 64;
    int u0  = blockIdx.y * 64;
    int b   = pt0 / HW;
    int rem0 = pt0 - b * HW;
    const float* gb = g + (size_t)(b * 2) * HW;

    #pragma unroll
    for (int it = 0; it < 16; it++){
        int idx = it * 256 + tid;
        int ur = idx >> 6, pc = idx & 63;
        int u = u0 + ur; int rem = rem0 + pc;
        const float* src; int sel;
        if (u < C){ src = key  + ((size_t)b * C + u) * HW;       sel = 0; }
        else      { src = newf + ((size_t)b * C + (u - C)) * HW; sel = 1; }
        float v = src[rem] * gb[(size_t)sel * HW + rem];
        tile[ur][pc] = f2bf(v);
    }
    __syncthreads();
    unsigned short* go = gin + (size_t)pt0 * (2 * C) + u0;
    #pragma unroll
    for (int it = 0; it < 16; it++){
        int idx = it * 256 + tid;
        int pr = idx >> 6, uc = idx & 63;
        go[(size_t)pr * (2 * C) + uc] = tile[uc][pr];
    }
}

// ============================================================
// prep_w: W[co][ci][t] fp32 -> Wt[co][t*Cin+ci] bf16
// ============================================================
__global__ void prep_w(const float* __restrict__ W, unsigned short* __restrict__ Wt,
                       int Cin){
    int ci = blockIdx.y * 256 + threadIdx.x;
    int bx = blockIdx.x;
    int co = bx / 9, t = bx - co * 9;
    Wt[(size_t)bx * Cin + ci] = f2bf(W[((size_t)co * Cin + ci) * 9 + t]);
}

// ============================================================
// conv_mfma v3: BM=64 (was 128) so every dispatch is 512 blocks =
// 2 blocks/CU (launch_bounds(256,2)) — co-resident block computes
// through the other's barrier drain. XOR-swizzled LDS, dbuf, 1 barrier.
// Wave grid 2x2: each wave 32 rows x BN/2 cols, acc[2][NJ].
// ============================================================
template<int BN, int EPI>
__global__ __launch_bounds__(256, 2)
void conv_mfma(const unsigned short* __restrict__ gin,
               const unsigned short* __restrict__ Wt,
               const float* __restrict__ bias,
               unsigned short* __restrict__ obf, int ostride,
               float* __restrict__ of32,
               const void* __restrict__ zp,
               int Cin, int Cout, int H, int W, int logHW, int logW)
{
    constexpr int BM = 64;
    constexpr int BNh = BN / 2;
    constexpr int NJ = BN / 32;
    __shared__ __align__(16) unsigned short sA[2][BM * 32];
    __shared__ __align__(16) unsigned short sB[2][BN * 32];

    const int tid = threadIdx.x;
    const int lane = tid & 63;
    const int wv = tid >> 6;
    const int wm = wv >> 1, wn = wv & 1;
    const int ln = lane & 15, q = lane >> 4;

    const int p0 = blockIdx.x * BM;
    const int b  = p0 >> logHW;
    const int rem0 = p0 - (b << logHW);

    // staging: row = tid>>2 (0..63); swizzled global chunk
    const int rowA0 = tid >> 2;
    const int gc8 = ((tid & 3) ^ ((tid >> 3) & 3)) * 8;    // element offset
    const int remA0 = rem0 + rowA0;
    const int yA0 = remA0 >> logW, xA0 = remA0 & (W - 1);
    const size_t pbase = ((size_t)b << logHW);

    const int nt0 = blockIdx.y * BN;
    const size_t Ktot = (size_t)9 * Cin;
    const unsigned short* wB0 = Wt + (size_t)(nt0 + rowA0) * Ktot + gc8;
    const unsigned short* wB1 = wB0 + 64 * Ktot;

    f4v acc[2][NJ];
    #pragma unroll
    for (int i = 0; i < 2; i++)
        #pragma unroll
        for (int j = 0; j < NJ; j++){ f4v z = {0.f, 0.f, 0.f, 0.f}; acc[i][j] = z; }

    const int cblocks = Cin >> 5;
    const int total = 9 * cblocks;

    // tap state for the tile currently being staged (t=0: dy=-1,dx=-1)
    int t_cur = 0;
    bool v0 = (yA0 > 0) && (xA0 > 0);
    const unsigned short* a0 = gin + (pbase + remA0 + (-W - 1)) * Cin + gc8;

    // prologue: stage K-block 0 into buf 0
    {
        gl_lds16(v0 ? (const void*)a0 : zp, (char*)sA[0] + wv * 1024);
        char* dB = (char*)sB[0];
        gl_lds16((const void*)wB0, dB + wv * 1024);
        if (BN == 128) gl_lds16((const void*)wB1, dB + 4096 + wv * 1024);
    }

    const int rchunk = (q ^ ((ln >> 1) & 3)) * 8;   // swizzled read offset
    int cb = 0;
    for (int kb = 0; kb < total; kb++){
        __syncthreads();   // buf[kb&1] loads (issued last iter) complete

        if (kb + 1 < total){
            int cbn = cb + 1;
            if (cbn == cblocks){
                cbn = 0;
                t_cur++;
                const int dy = t_cur / 3 - 1, dx = t_cur % 3 - 1;
                const int dof = dy * W + dx;
                v0 = ((unsigned)(yA0 + dy) < (unsigned)H) && ((unsigned)(xA0 + dx) < (unsigned)W);
                a0 = gin + (pbase + remA0 + dof) * Cin + gc8;
            }
            const int nb = (kb + 1) & 1;
            gl_lds16(v0 ? (const void*)(a0 + cbn * 32) : zp, (char*)sA[nb] + wv * 1024);
            char* dB = (char*)sB[nb];
            gl_lds16((const void*)(wB0 + (kb + 1) * 32), dB + wv * 1024);
            if (BN == 128) gl_lds16((const void*)(wB1 + (kb + 1) * 32), dB + 4096 + wv * 1024);
            cb = cbn;
        }

        const unsigned short* A = sA[kb & 1];
        const unsigned short* B = sB[kb & 1];
        s8v af[2];
        #pragma unroll
        for (int i = 0; i < 2; i++)
            af[i] = *(const s8v*)(A + (wm * 32 + i * 16 + ln) * 32 + rchunk);
        #pragma unroll
        for (int j = 0; j < NJ; j++){
            s8v bfr = *(const s8v*)(B + (wn * BNh + j * 16 + ln) * 32 + rchunk);
            #pragma unroll
            for (int i = 0; i < 2; i++)
                acc[i][j] = mfma16(af[i], bfr, acc[i][j]);
        }
    }

    // epilogue: D rows m = q*4+r (pixels), cols n = ln (cout)
    #pragma unroll
    for (int i = 0; i < 2; i++){
        const int m0 = wm * 32 + i * 16 + q * 4;
        const int p = p0 + m0;
        #pragma unroll
        for (int j = 0; j < NJ; j++){
            const int n = nt0 + wn * BNh + j * 16 + ln;
            const float bv = bias[n];
            if (EPI == 0){
                #pragma unroll
                for (int r = 0; r < 4; r++){
                    float v = fmaxf(acc[i][j][r] + bv, 0.f);
                    obf[(size_t)(p + r) * ostride + n] = f2bf(v);
                }
            } else {
                f4v o;
                #pragma unroll
                for (int r = 0; r < 4; r++) o[r] = fmaxf(acc[i][j][r] + bv, 0.f);
                const int rem = rem0 + m0;
                *(f4v*)(of32 + (((size_t)b * Cout + n) << logHW) + rem) = o;
            }
        }
    }
}

// ============================================================
extern "C" void kernel_launch(void* const* d_in, const int* in_sizes, int n_in,
                              void* d_out, int out_size, void* d_ws, size_t ws_size,
                              hipStream_t stream){
    (void)in_sizes; (void)n_in; (void)out_size; (void)ws_size;

    const float* X[4][2];
    for (int s = 0; s < 4; s++)
        for (int l = 0; l < 2; l++)
            X[s][l] = (const float*)d_in[s * 2 + l];
    const float* Wg[2] = { (const float*)d_in[8],  (const float*)d_in[14] };
    const float* bg[2] = { (const float*)d_in[9],  (const float*)d_in[15] };
    const float* Wd[2] = { (const float*)d_in[10], (const float*)d_in[16] };
    const float* bd[2] = { (const float*)d_in[11], (const float*)d_in[17] };
    const float* Wc[2] = { (const float*)d_in[12], (const float*)d_in[18] };
    const float* bc[2] = { (const float*)d_in[13], (const float*)d_in[19] };
    float* out = (float*)d_out;

    char* ws = (char*)d_ws;
    unsigned* gmax = (unsigned*)ws;
    const void* zp = (const void*)(ws + 1024);
    float* corrbuf = (float*)(ws + 4096);
    float* newbuf  = (float*)(ws + 4096 + 1638400);
    unsigned short* wtbuf = (unsigned short*)newbuf;   // alias, disjoint lifetime
    float* gbuf    = (float*)(ws + 4096 + 1638400 + 16777216);
    unsigned short* ginbuf = (unsigned short*)(ws + 4096 + 1638400 + 16777216 + 131072);
    unsigned short* totbuf = (unsigned short*)(ws + 4096 + 1638400 + 16777216 + 131072 + 16777216);

    hipMemsetAsync(ws, 0, 4096, stream);

    const int Cs[2] = {256, 512};
    const int Hs[2] = {64, 32};
    const int logWs[2] = {6, 5};
    const int logHWs[2] = {12, 10};
    const size_t outOff[2] = {0, (size_t)4 * 256 * 4096};

    for (int l = 0; l < 2; l++){
        const int C = Cs[l], H = Hs[l], W = Hs[l], HW = H * W;
        const int logW = logWs[l], logHW = logHWs[l];
        const float* key = X[3][l];
        const int pblk = 4 * HW / 256;
        const dim3 gblk(64, 4);
        const int Mt = 4 * HW / 64;            // BM=64 tiles

        for (int s = 0; s < 3; s++){
            const float* fr = X[s][l];
            unsigned* slot = gmax + (l * 3 + s);
            corr_kernel<<<dim3(25, pblk), 256, 0, stream>>>(
                key, fr, corrbuf, slot, C, H, W, logHW, logW);
            att_kernel<<<pblk, 256, 0, stream>>>(corrbuf, slot, logHW);
            warp_gather<<<dim3(pblk, C), 256, 0, stream>>>(
                fr, corrbuf, newbuf, C, H, W, logHW, logW);
            gate_kernel<<<4 * HW / 64, gblk, 0, stream>>>(
                key, newbuf, Wg[l] + (size_t)s * 2 * (2 * C) * 9,
                bg[l] + (size_t)s * 2, gbuf, C, H, W);
            prep_gin<<<dim3(4 * HW / 64, 2 * C / 64), 256, 0, stream>>>(
                key, newbuf, gbuf, ginbuf, C, HW);
            prep_w<<<dim3(C * 9, 2 * C / 256), 256, 0, stream>>>(
                Wd[l] + (size_t)s * C * 2 * C * 9, wtbuf, 2 * C);
            if (l == 0)
                conv_mfma<128, 0><<<dim3(Mt, C / 128), 256, 0, stream>>>(
                    ginbuf, wtbuf, bd[l] + s * C, totbuf + s * C, 3 * C,
                    nullptr, zp, 2 * C, C, H, W, logHW, logW);
            else
                conv_mfma<64, 0><<<dim3(Mt, C / 64), 256, 0, stream>>>(
                    ginbuf, wtbuf, bd[l] + s * C, totbuf + s * C, 3 * C,
                    nullptr, zp, 2 * C, C, H, W, logHW, logW);
        }
        prep_w<<<dim3(C * 9, 3 * C / 256), 256, 0, stream>>>(Wc[l], wtbuf, 3 * C);
        if (l == 0)
            conv_mfma<128, 1><<<dim3(Mt, 2), 256, 0, stream>>>(
                totbuf, wtbuf, bc[l], nullptr, 0,
                out + outOff[l], zp, 3 * C, C, H, W, logHW, logW);
        else
            conv_mfma<64, 1><<<dim3(Mt, 8), 256, 0, stream>>>(
                totbuf, wtbuf, bc[l], nullptr, 0,
                out + outOff[l], zp, 3 * C, C, H, W, logHW, logW);
    }
}